// Round 1
// baseline (380.068 us; speedup 1.0000x reference)
//
#include <hip/hip_runtime.h>

// Workspace layout (float offsets)
#define WS_M2 0          // 16384 floats  (512 x 32)
#define WS_N2 16384      // 2048  floats  (64 x 32)
#define WS_WT 18432      // 131072 floats (32 x 4096), W transposed: Wt[r*4096+o]
#define WS_Z  149504     // 32768 floats  (1024 x 32)
// total 182272 floats = 729088 bytes

// ---------------------------------------------------------------------------
// Kernel A: collapse TT factor chains into small dense matrices.
//   block 0    : M2 (512x32) and N2 (64x32)
//   blocks 1-32: Wt (32x4096), each block does a 128-wide o-slice
// ---------------------------------------------------------------------------
__global__ __launch_bounds__(256) void precompute_kernel(
    const float* __restrict__ f0, const float* __restrict__ f1,
    const float* __restrict__ f2, const float* __restrict__ f3,
    const float* __restrict__ f4, const float* __restrict__ g0,
    const float* __restrict__ g1, const float* __restrict__ g2,
    float* __restrict__ ws)
{
    __shared__ float sA[8192];
    const int t = threadIdx.x;
    const int blk = blockIdx.x;
    if (blk == 0) {
        // M1[a0a1, r2] = sum_r1 f0[a0,r1] * f1[r1,a1,r2]   (64x32) in LDS
        for (int i = t; i < 2048; i += 256) {
            int a01 = i >> 5, r2 = i & 31;
            int a0 = a01 >> 3, a1 = a01 & 7;
            float s = 0.f;
            #pragma unroll
            for (int r1 = 0; r1 < 32; ++r1)
                s += f0[a0*32 + r1] * f1[r1*256 + a1*32 + r2];
            sA[i] = s;
        }
        __syncthreads();
        // M2[a0a1a2, r3] = sum_r2 M1[a0a1, r2] * f2[r2,a2,r3]   (512x32)
        for (int i = t; i < 16384; i += 256) {
            int a012 = i >> 5, r3 = i & 31;
            int a01 = a012 >> 3, a2 = a012 & 7;
            float s = 0.f;
            #pragma unroll
            for (int r2 = 0; r2 < 32; ++r2)
                s += sA[a01*32 + r2] * f2[r2*256 + a2*32 + r3];
            ws[WS_M2 + i] = s;
        }
        // N2[a3a4, s2] = sum_s1 f3[a3,s1] * f4[s1,a4,s2]   (64x32)
        for (int i = t; i < 2048; i += 256) {
            int a34 = i >> 5, s2 = i & 31;
            int a3 = a34 >> 3, a4 = a34 & 7;
            float s = 0.f;
            #pragma unroll
            for (int s1 = 0; s1 < 32; ++s1)
                s += f3[a3*32 + s1] * f4[s1*256 + a4*32 + s2];
            ws[WS_N2 + i] = s;
        }
    } else {
        const int j = blk - 1;   // 0..31, o-slice
        // W2[o0o1, q] = sum_p g0[o0,p] * g1[p,o1,q]   (256x32) in LDS
        for (int i = t; i < 8192; i += 256) {
            int o01 = i >> 5, q = i & 31;
            int o0 = o01 >> 4, o1 = o01 & 15;
            float s = 0.f;
            #pragma unroll
            for (int p = 0; p < 32; ++p)
                s += g0[o0*32 + p] * g1[p*512 + o1*32 + q];
            sA[i] = s;
        }
        __syncthreads();
        // Wt[r, o] = sum_q W2[o>>4, q] * g2[q, o&15, r]
        for (int i = t; i < 4096; i += 256) {
            int o = j*128 + (i >> 5);
            int r = i & 31;
            int o01 = o >> 4, o2 = o & 15;
            float s = 0.f;
            #pragma unroll
            for (int q = 0; q < 32; ++q)
                s += sA[o01*32 + q] * g2[q*512 + o2*32 + r];
            ws[WS_WT + r*4096 + o] = s;
        }
    }
}

// ---------------------------------------------------------------------------
// Kernel B: one block per batch element b.
//   phase 1: T3[m,r3] = sum_k x[b,k,m] * M2[k,r3]   (m=64 (a3,a4), k=512, r3=32)
//   phase 3: T5[r3,s2] = sum_m T3[m,r3] * N2[m,s2]
//   phase 4: z[ro]    = sum_{k<1024} T5[k] * core[k,ro]
// ---------------------------------------------------------------------------
__global__ __launch_bounds__(256) void main_kernel(
    const float* __restrict__ x, const float* __restrict__ core,
    const float* __restrict__ ws, float* __restrict__ zout)
{
    __shared__ float sm[16384];              // 64 KB, phase-reused
    const int t = threadIdx.x;
    const int b = blockIdx.x;

    // stage M2 (512x32) into LDS, coalesced float4
    {
        const float4* m24 = (const float4*)(ws + WS_M2);
        float4* sm4 = (float4*)sm;
        #pragma unroll
        for (int i = 0; i < 16; ++i)
            sm4[i*256 + t] = m24[i*256 + t];
    }
    __syncthreads();

    // phase 1: thread owns m = 4*(t&15)..+3, r3 = 2*(t>>4)..+1
    const int m4 = t & 15;
    const int rg = t >> 4;        // 0..15
    float acc[4][2] = {{0.f,0.f},{0.f,0.f},{0.f,0.f},{0.f,0.f}};
    const float4* x4 = (const float4*)(x + (size_t)b * 32768);
    #pragma unroll 8
    for (int k = 0; k < 512; ++k) {
        float4 xv = x4[k*16 + m4];
        float2 wv = *(const float2*)&sm[k*32 + rg*2];
        acc[0][0] += xv.x * wv.x; acc[0][1] += xv.x * wv.y;
        acc[1][0] += xv.y * wv.x; acc[1][1] += xv.y * wv.y;
        acc[2][0] += xv.z * wv.x; acc[2][1] += xv.z * wv.y;
        acc[3][0] += xv.w * wv.x; acc[3][1] += xv.w * wv.y;
    }
    __syncthreads();

    // phase 2: T3 -> sm[0..2048), N2 -> sm[2048..4096)
    #pragma unroll
    for (int jj = 0; jj < 4; ++jj) {
        sm[(m4*4 + jj)*32 + rg*2 + 0] = acc[jj][0];
        sm[(m4*4 + jj)*32 + rg*2 + 1] = acc[jj][1];
    }
    {
        const float4* n24 = (const float4*)(ws + WS_N2);
        float4* d = (float4*)(sm + 2048);
        d[t]       = n24[t];
        d[256 + t] = n24[256 + t];
    }
    __syncthreads();

    // phase 3: T5 -> sm[4096..5120)
    {
        const int r3  = t >> 3;
        const int s2b = (t & 7) * 4;
        float a0=0.f, a1=0.f, a2=0.f, a3=0.f;
        #pragma unroll 8
        for (int m = 0; m < 64; ++m) {
            float av = sm[m*32 + r3];
            const float* n = &sm[2048 + m*32 + s2b];
            a0 += av * n[0]; a1 += av * n[1]; a2 += av * n[2]; a3 += av * n[3];
        }
        float* d = &sm[4096 + r3*32 + s2b];
        d[0]=a0; d[1]=a1; d[2]=a2; d[3]=a3;
    }
    __syncthreads();

    // phase 4: z[ro] = sum_k T5[k] * core[k,ro], split k over 8 groups
    {
        const int ro = t & 31;
        const int kc = t >> 5;    // 0..7
        float s = 0.f;
        const int k0 = kc * 128;
        for (int k = k0; k < k0 + 128; ++k)
            s += sm[4096 + k] * core[k*32 + ro];
        sm[5120 + kc*32 + ro] = s;
    }
    __syncthreads();
    if (t < 32) {
        float s = 0.f;
        #pragma unroll
        for (int kc = 0; kc < 8; ++kc) s += sm[5120 + kc*32 + t];
        zout[b*32 + t] = s;
    }
}

// ---------------------------------------------------------------------------
// Kernel C: out[b,o] = sum_r z[b,r] * Wt[r,o] + bias[o]
//   grid (16 b-tiles of 64, 16 o-tiles of 256), 256 threads
// ---------------------------------------------------------------------------
__global__ __launch_bounds__(256) void out_kernel(
    const float* __restrict__ ws, const float* __restrict__ bias,
    float* __restrict__ out)
{
    __shared__ float sW[8192];   // Wt tile [32][256]
    __shared__ float sZ[2048];   // z tile  [64][32]
    __shared__ float sB[256];    // bias tile
    const int t  = threadIdx.x;
    const int bt = blockIdx.x;   // b-tile
    const int ot = blockIdx.y;   // o-tile

    {
        const float4* wt4 = (const float4*)(ws + WS_WT);
        float4* d = (float4*)sW;
        #pragma unroll
        for (int i = 0; i < 8; ++i) {
            int idx = i*256 + t;              // 0..2047
            int ro = idx >> 6, oc = idx & 63;
            d[idx] = wt4[ro*1024 + ot*64 + oc];
        }
    }
    {
        const float4* z4 = (const float4*)(ws + WS_Z) + bt*512;
        float4* d = (float4*)sZ;
        d[t]       = z4[t];
        d[256 + t] = z4[256 + t];
    }
    if (t < 64) {
        const float4* b4 = (const float4*)bias + ot*64;
        ((float4*)sB)[t] = b4[t];
    }
    __syncthreads();

    const int oc = t & 63;       // float4 column within o-tile
    const int bg = t >> 6;       // 0..3 -> 16 b's each
    const float4* sW4 = (const float4*)sW;
    const float4 bv = ((const float4*)sB)[oc];
    float4* out4 = (float4*)out;

    for (int bi = 0; bi < 16; bi += 4) {
        const int bl = bg*16 + bi;
        float4 a0 = bv, a1 = bv, a2 = bv, a3 = bv;
        #pragma unroll
        for (int ro = 0; ro < 32; ++ro) {
            float4 w = sW4[ro*64 + oc];
            float z0 = sZ[(bl+0)*32 + ro];
            float z1 = sZ[(bl+1)*32 + ro];
            float z2 = sZ[(bl+2)*32 + ro];
            float z3 = sZ[(bl+3)*32 + ro];
            a0.x += z0*w.x; a0.y += z0*w.y; a0.z += z0*w.z; a0.w += z0*w.w;
            a1.x += z1*w.x; a1.y += z1*w.y; a1.z += z1*w.z; a1.w += z1*w.w;
            a2.x += z2*w.x; a2.y += z2*w.y; a2.z += z2*w.z; a2.w += z2*w.w;
            a3.x += z3*w.x; a3.y += z3*w.y; a3.z += z3*w.z; a3.w += z3*w.w;
        }
        const size_t obase = (size_t)(bt*64 + bl) * 1024 + ot*64 + oc;
        out4[obase + 0*1024] = a0;
        out4[obase + 1*1024] = a1;
        out4[obase + 2*1024] = a2;
        out4[obase + 3*1024] = a3;
    }
}

extern "C" void kernel_launch(void* const* d_in, const int* in_sizes, int n_in,
                              void* d_out, int out_size, void* d_ws, size_t ws_size,
                              hipStream_t stream)
{
    const float* x    = (const float*)d_in[0];
    const float* f0   = (const float*)d_in[1];
    const float* f1   = (const float*)d_in[2];
    const float* f2   = (const float*)d_in[3];
    const float* f3   = (const float*)d_in[4];
    const float* f4   = (const float*)d_in[5];
    const float* core = (const float*)d_in[6];
    const float* g0   = (const float*)d_in[7];
    const float* g1   = (const float*)d_in[8];
    const float* g2   = (const float*)d_in[9];
    const float* bias = (const float*)d_in[10];
    float* ws  = (float*)d_ws;
    float* out = (float*)d_out;

    precompute_kernel<<<33, 256, 0, stream>>>(f0, f1, f2, f3, f4, g0, g1, g2, ws);
    main_kernel<<<1024, 256, 0, stream>>>(x, core, ws, ws + WS_Z);
    out_kernel<<<dim3(16, 16), 256, 0, stream>>>(ws, bias, out);
}

// Round 2
// 267.972 us; speedup vs baseline: 1.4183x; 1.4183x over previous
//
#include <hip/hip_runtime.h>

// Workspace layout (float offsets)
#define WS_M2 0          // 16384 floats  (512 x 32)
#define WS_N2 16384      // 2048  floats  (64 x 32)
#define WS_WT 18432      // 131072 floats (32 x 4096), W transposed: Wt[r*4096+o]
#define WS_Z  149504     // 32768 floats  (1024 x 32)
// total 182272 floats = 729088 bytes

// ---------------------------------------------------------------------------
// Kernel A: collapse TT factor chains into small dense matrices.
//   blocks 0-7 : M2 (512x32), each block computes 64 rows (M1 recomputed, cheap)
//   block  8   : N2 (64x32)
//   blocks 9-40: Wt (32x4096), each block a 128-wide o-slice
// ---------------------------------------------------------------------------
__global__ __launch_bounds__(256) void precompute_kernel(
    const float* __restrict__ f0, const float* __restrict__ f1,
    const float* __restrict__ f2, const float* __restrict__ f3,
    const float* __restrict__ f4, const float* __restrict__ g0,
    const float* __restrict__ g1, const float* __restrict__ g2,
    float* __restrict__ ws)
{
    __shared__ float sA[8192];
    const int t = threadIdx.x;
    const int blk = blockIdx.x;
    if (blk < 8) {
        // M1[a0a1, r2] = sum_r1 f0[a0,r1] * f1[r1,a1,r2]   (64x32) in LDS
        for (int i = t; i < 2048; i += 256) {
            int a01 = i >> 5, r2 = i & 31;
            int a0 = a01 >> 3, a1 = a01 & 7;
            float s = 0.f;
            #pragma unroll
            for (int r1 = 0; r1 < 32; ++r1)
                s += f0[a0*32 + r1] * f1[r1*256 + a1*32 + r2];
            sA[i] = s;
        }
        __syncthreads();
        // M2 slice: rows a012 in [blk*64, blk*64+64)
        for (int i = t; i < 2048; i += 256) {
            int a012 = blk*64 + (i >> 5), r3 = i & 31;
            int a01 = a012 >> 3, a2 = a012 & 7;
            float s = 0.f;
            #pragma unroll
            for (int r2 = 0; r2 < 32; ++r2)
                s += sA[a01*32 + r2] * f2[r2*256 + a2*32 + r3];
            ws[WS_M2 + a012*32 + r3] = s;
        }
    } else if (blk == 8) {
        // N2[a3a4, s2] = sum_s1 f3[a3,s1] * f4[s1,a4,s2]   (64x32)
        for (int i = t; i < 2048; i += 256) {
            int a34 = i >> 5, s2 = i & 31;
            int a3 = a34 >> 3, a4 = a34 & 7;
            float s = 0.f;
            #pragma unroll
            for (int s1 = 0; s1 < 32; ++s1)
                s += f3[a3*32 + s1] * f4[s1*256 + a4*32 + s2];
            ws[WS_N2 + i] = s;
        }
    } else {
        const int j = blk - 9;   // 0..31, o-slice
        // W2[o0o1, q] = sum_p g0[o0,p] * g1[p,o1,q]   (256x32) in LDS
        for (int i = t; i < 8192; i += 256) {
            int o01 = i >> 5, q = i & 31;
            int o0 = o01 >> 4, o1 = o01 & 15;
            float s = 0.f;
            #pragma unroll
            for (int p = 0; p < 32; ++p)
                s += g0[o0*32 + p] * g1[p*512 + o1*32 + q];
            sA[i] = s;
        }
        __syncthreads();
        // Wt[r, o] = sum_q W2[o>>4, q] * g2[q, o&15, r]
        for (int i = t; i < 4096; i += 256) {
            int o = j*128 + (i >> 5);
            int r = i & 31;
            int o01 = o >> 4, o2 = o & 15;
            float s = 0.f;
            #pragma unroll
            for (int q = 0; q < 32; ++q)
                s += sA[o01*32 + q] * g2[q*512 + o2*32 + r];
            ws[WS_WT + r*4096 + o] = s;
        }
    }
}

// ---------------------------------------------------------------------------
// Kernel B: one block per batch element b.  k chunked 8x64; x + M2 chunks
// staged in LDS via coalesced float4 (zero redundant global traffic).
//   phase 1: T3[m,r3] = sum_k x[b,k,m] * M2[k,r3]   (m=64, k=512, r3=32)
//   phase 3: T5[r3,s2] = sum_m T3[m,r3] * N2[m,s2]
//   phase 4: z[ro]    = sum_{k<1024} T5[k] * core[k,ro]
// LDS: 32 KB -> 4+ blocks/CU (grid = exactly 4 blocks/CU on 256 CUs)
// ---------------------------------------------------------------------------
__global__ __launch_bounds__(256) void main_kernel(
    const float* __restrict__ x, const float* __restrict__ core,
    const float* __restrict__ ws, float* __restrict__ zout)
{
    __shared__ float sx[4096];   // x chunk: 64 k x 64 m ; later T3 (pitch 33)
    __shared__ float sM[2048];   // M2 chunk: 64 k x 32  ; later T5 + partials
    __shared__ float sN[2048];   // N2 (loaded once at start)
    const int t = threadIdx.x;
    const int b = blockIdx.x;

    float4* sx4 = (float4*)sx;
    float4* sM4 = (float4*)sM;

    // stage N2 once (sN untouched until phase 3)
    {
        const float4* n24 = (const float4*)(ws + WS_N2);
        float4* d = (float4*)sN;
        d[t]       = n24[t];
        d[256 + t] = n24[256 + t];
    }

    // phase 1: thread owns m = 4*(t&15)..+3, r3 = 2*(t>>4)..+1
    const int m4 = t & 15;
    const int rg = t >> 4;        // 0..15
    float acc[4][2] = {{0.f,0.f},{0.f,0.f},{0.f,0.f},{0.f,0.f}};
    const float4* x4 = (const float4*)(x + (size_t)b * 32768);
    const float4* m24 = (const float4*)(ws + WS_M2);

    for (int c = 0; c < 8; ++c) {
        // coalesced chunk staging: x 4096 floats, M2 2048 floats
        const float4* xs = x4 + c*1024;
        #pragma unroll
        for (int i = 0; i < 4; ++i) sx4[i*256 + t] = xs[i*256 + t];
        const float4* ms = m24 + c*512;
        #pragma unroll
        for (int i = 0; i < 2; ++i) sM4[i*256 + t] = ms[i*256 + t];
        __syncthreads();

        #pragma unroll 16
        for (int k = 0; k < 64; ++k) {
            float4 xv = sx4[k*16 + m4];
            float2 wv = *(const float2*)&sM[k*32 + rg*2];
            acc[0][0] += xv.x * wv.x; acc[0][1] += xv.x * wv.y;
            acc[1][0] += xv.y * wv.x; acc[1][1] += xv.y * wv.y;
            acc[2][0] += xv.z * wv.x; acc[2][1] += xv.z * wv.y;
            acc[3][0] += xv.w * wv.x; acc[3][1] += xv.w * wv.y;
        }
        __syncthreads();
    }

    // phase 2: T3 -> sx with pitch 33 (bank-conflict-free phase-3 reads)
    #pragma unroll
    for (int j = 0; j < 4; ++j) {
        sx[(m4*4 + j)*33 + rg*2 + 0] = acc[j][0];
        sx[(m4*4 + j)*33 + rg*2 + 1] = acc[j][1];
    }
    __syncthreads();

    // phase 3: T5[r3,s2] -> sM[0..1024)
    {
        const int r3  = t >> 3;
        const int s2b = (t & 7) * 4;
        float a0=0.f, a1=0.f, a2=0.f, a3=0.f;
        #pragma unroll 8
        for (int m = 0; m < 64; ++m) {
            float av = sx[m*33 + r3];
            const float* n = &sN[m*32 + s2b];
            a0 += av * n[0]; a1 += av * n[1]; a2 += av * n[2]; a3 += av * n[3];
        }
        float* d = &sM[r3*32 + s2b];
        d[0]=a0; d[1]=a1; d[2]=a2; d[3]=a3;
    }
    __syncthreads();

    // phase 4: z[ro] = sum_k T5[k] * core[k,ro]; 16 k-slices x 16 ro-pairs
    {
        const int ro2 = t & 15;       // float2 column pair
        const int kc  = t >> 4;       // 0..15 -> 64 k each
        const float2* core2 = (const float2*)core;
        float s0 = 0.f, s1 = 0.f;
        const int k0 = kc * 64;
        for (int k = k0; k < k0 + 64; ++k) {
            float tv = sM[k];
            float2 cv = core2[k*16 + ro2];
            s0 += tv * cv.x; s1 += tv * cv.y;
        }
        sM[1024 + kc*32 + ro2*2 + 0] = s0;
        sM[1024 + kc*32 + ro2*2 + 1] = s1;
    }
    __syncthreads();
    if (t < 32) {
        float s = 0.f;
        #pragma unroll
        for (int kc = 0; kc < 16; ++kc) s += sM[1024 + kc*32 + t];
        zout[b*32 + t] = s;
    }
}

// ---------------------------------------------------------------------------
// Kernel C: out[b,o] = sum_r z[b,r] * Wt[r,o] + bias[o]
//   grid (16 b-tiles of 64, 16 o-tiles of 256), 256 threads
//   z tile stored transposed (pitch 68) so z reads are float4 broadcasts
// ---------------------------------------------------------------------------
__global__ __launch_bounds__(256) void out_kernel(
    const float* __restrict__ ws, const float* __restrict__ bias,
    float* __restrict__ out)
{
    __shared__ float sW[8192];   // Wt tile [32][256]
    __shared__ float sZt[2176];  // z tile transposed [32 ro][68] (64 b used)
    __shared__ float sB[256];    // bias tile
    const int t  = threadIdx.x;
    const int bt = blockIdx.x;   // b-tile
    const int ot = blockIdx.y;   // o-tile

    {
        const float4* wt4 = (const float4*)(ws + WS_WT);
        float4* d = (float4*)sW;
        #pragma unroll
        for (int i = 0; i < 8; ++i) {
            int idx = i*256 + t;              // 0..2047
            int ro = idx >> 6, oc = idx & 63;
            d[idx] = wt4[ro*1024 + ot*64 + oc];
        }
    }
    {
        // load z tile coalesced, scatter transposed into sZt
        const float4* z4 = (const float4*)(ws + WS_Z) + bt*512;
        #pragma unroll
        for (int i = 0; i < 2; ++i) {
            int idx = i*256 + t;              // 0..511
            int bl = idx >> 3, r4 = idx & 7;  // b-local, ro-quad
            float4 v = z4[idx];
            sZt[(r4*4 + 0)*68 + bl] = v.x;
            sZt[(r4*4 + 1)*68 + bl] = v.y;
            sZt[(r4*4 + 2)*68 + bl] = v.z;
            sZt[(r4*4 + 3)*68 + bl] = v.w;
        }
    }
    if (t < 64) {
        const float4* b4 = (const float4*)bias + ot*64;
        ((float4*)sB)[t] = b4[t];
    }
    __syncthreads();

    const int oc = t & 63;       // float4 column within o-tile
    const int bg = t >> 6;       // 0..3 -> 16 b's each
    const float4* sW4 = (const float4*)sW;
    const float4 bv = ((const float4*)sB)[oc];
    float4* out4 = (float4*)out;

    for (int bi = 0; bi < 16; bi += 4) {
        const int bl = bg*16 + bi;
        float4 a0 = bv, a1 = bv, a2 = bv, a3 = bv;
        #pragma unroll
        for (int ro = 0; ro < 32; ++ro) {
            float4 w = sW4[ro*64 + oc];
            float4 z = *(const float4*)&sZt[ro*68 + bl];  // broadcast, 16B-aligned
            a0.x += z.x*w.x; a0.y += z.x*w.y; a0.z += z.x*w.z; a0.w += z.x*w.w;
            a1.x += z.y*w.x; a1.y += z.y*w.y; a1.z += z.y*w.z; a1.w += z.y*w.w;
            a2.x += z.z*w.x; a2.y += z.z*w.y; a2.z += z.z*w.z; a2.w += z.z*w.w;
            a3.x += z.w*w.x; a3.y += z.w*w.y; a3.z += z.w*w.z; a3.w += z.w*w.w;
        }
        const size_t obase = (size_t)(bt*64 + bl) * 1024 + ot*64 + oc;
        out4[obase + 0*1024] = a0;
        out4[obase + 1*1024] = a1;
        out4[obase + 2*1024] = a2;
        out4[obase + 3*1024] = a3;
    }
}

extern "C" void kernel_launch(void* const* d_in, const int* in_sizes, int n_in,
                              void* d_out, int out_size, void* d_ws, size_t ws_size,
                              hipStream_t stream)
{
    const float* x    = (const float*)d_in[0];
    const float* f0   = (const float*)d_in[1];
    const float* f1   = (const float*)d_in[2];
    const float* f2   = (const float*)d_in[3];
    const float* f3   = (const float*)d_in[4];
    const float* f4   = (const float*)d_in[5];
    const float* core = (const float*)d_in[6];
    const float* g0   = (const float*)d_in[7];
    const float* g1   = (const float*)d_in[8];
    const float* g2   = (const float*)d_in[9];
    const float* bias = (const float*)d_in[10];
    float* ws  = (float*)d_ws;
    float* out = (float*)d_out;

    precompute_kernel<<<41, 256, 0, stream>>>(f0, f1, f2, f3, f4, g0, g1, g2, ws);
    main_kernel<<<1024, 256, 0, stream>>>(x, core, ws, ws + WS_Z);
    out_kernel<<<dim3(16, 16), 256, 0, stream>>>(ws, bias, out);
}

// Round 3
// 266.404 us; speedup vs baseline: 1.4267x; 1.0059x over previous
//
#include <hip/hip_runtime.h>

// Workspace layout (float offsets)
#define WS_M2 0          // 16384 floats  (512 x 32)
#define WS_N2 16384      // 2048  floats  (64 x 32)
#define WS_WT 18432      // 131072 floats (32 x 4096), W transposed: Wt[r*4096+o]
#define WS_Z  149504     // 32768 floats  (1024 x 32)

// ---------------------------------------------------------------------------
// Kernel A: collapse TT factor chains into small dense matrices.
// ---------------------------------------------------------------------------
__global__ __launch_bounds__(256) void precompute_kernel(
    const float* __restrict__ f0, const float* __restrict__ f1,
    const float* __restrict__ f2, const float* __restrict__ f3,
    const float* __restrict__ f4, const float* __restrict__ g0,
    const float* __restrict__ g1, const float* __restrict__ g2,
    float* __restrict__ ws)
{
    __shared__ float sA[8192];
    const int t = threadIdx.x;
    const int blk = blockIdx.x;
    if (blk < 8) {
        for (int i = t; i < 2048; i += 256) {
            int a01 = i >> 5, r2 = i & 31;
            int a0 = a01 >> 3, a1 = a01 & 7;
            float s = 0.f;
            #pragma unroll
            for (int r1 = 0; r1 < 32; ++r1)
                s += f0[a0*32 + r1] * f1[r1*256 + a1*32 + r2];
            sA[i] = s;
        }
        __syncthreads();
        for (int i = t; i < 2048; i += 256) {
            int a012 = blk*64 + (i >> 5), r3 = i & 31;
            int a01 = a012 >> 3, a2 = a012 & 7;
            float s = 0.f;
            #pragma unroll
            for (int r2 = 0; r2 < 32; ++r2)
                s += sA[a01*32 + r2] * f2[r2*256 + a2*32 + r3];
            ws[WS_M2 + a012*32 + r3] = s;
        }
    } else if (blk == 8) {
        for (int i = t; i < 2048; i += 256) {
            int a34 = i >> 5, s2 = i & 31;
            int a3 = a34 >> 3, a4 = a34 & 7;
            float s = 0.f;
            #pragma unroll
            for (int s1 = 0; s1 < 32; ++s1)
                s += f3[a3*32 + s1] * f4[s1*256 + a4*32 + s2];
            ws[WS_N2 + i] = s;
        }
    } else {
        const int j = blk - 9;   // 0..31, o-slice
        for (int i = t; i < 8192; i += 256) {
            int o01 = i >> 5, q = i & 31;
            int o0 = o01 >> 4, o1 = o01 & 15;
            float s = 0.f;
            #pragma unroll
            for (int p = 0; p < 32; ++p)
                s += g0[o0*32 + p] * g1[p*512 + o1*32 + q];
            sA[i] = s;
        }
        __syncthreads();
        for (int i = t; i < 4096; i += 256) {
            int o = j*128 + (i >> 5);
            int r = i & 31;
            int o01 = o >> 4, o2 = o & 15;
            float s = 0.f;
            #pragma unroll
            for (int q = 0; q < 32; ++q)
                s += sA[o01*32 + q] * g2[q*512 + o2*32 + r];
            ws[WS_WT + r*4096 + o] = s;
        }
    }
}

// ---------------------------------------------------------------------------
// Kernel B: one block per batch element.
//   phase 1: T3[m,r] = sum_k x[b,k,m]*M2[k,r]  (m=64,k=512,r=32)
//     8m x 4r register tile per thread, k split over the 4 waves (tk),
//     per k: 3x ds_read_b128 -> 32 FMA  (10.7 FMA / LDS instr)
//   reduce over tk via LDS, then phase 3 (T5) and phase 4 (z) as before.
// LDS: buf[8192] + 1536 = ~38 KB -> 4 blocks/CU co-resident.
// ---------------------------------------------------------------------------
__global__ __launch_bounds__(256, 4) void main_kernel(
    const float* __restrict__ x, const float* __restrict__ core,
    const float* __restrict__ ws, float* __restrict__ zout)
{
    __shared__ float buf[8192];   // phase1: x-chunk[0..4096)+M2-chunk[4096..6144)
                                  // reduce: 4 x 2048 partial T3
                                  // phase3: T3[0..2048) + N2[2048..4096) + T5[4096..5120)
    __shared__ float spart[512];  // phase-4 partials
    const int t = threadIdx.x;
    const int b = blockIdx.x;

    const int tk = t >> 6;         // wave id = k-quarter
    const int tm = (t >> 3) & 7;   // m-group of 8
    const int tr = t & 7;          // r-group of 4

    float4* buf4 = (float4*)buf;
    const float4* x4  = (const float4*)(x + (size_t)b * 32768);
    const float4* m24 = (const float4*)(ws + WS_M2);

    float acc[8][4];
    #pragma unroll
    for (int i = 0; i < 8; ++i)
        #pragma unroll
        for (int j = 0; j < 4; ++j) acc[i][j] = 0.f;

    for (int c = 0; c < 8; ++c) {
        // stage x chunk (64k x 64m = 1024 f4) and M2 chunk (64k x 32 = 512 f4)
        const float4* xs = x4 + c*1024;
        #pragma unroll
        for (int i = 0; i < 4; ++i) buf4[i*256 + t] = xs[i*256 + t];
        const float4* ms = m24 + c*512;
        #pragma unroll
        for (int i = 0; i < 2; ++i) buf4[1024 + i*256 + t] = ms[i*256 + t];
        __syncthreads();

        #pragma unroll 4
        for (int k0 = 0; k0 < 16; ++k0) {
            const int k = tk*16 + k0;
            float4 xa = buf4[k*16 + tm*2];
            float4 xb = buf4[k*16 + tm*2 + 1];
            float4 wv = buf4[1024 + k*8 + tr];
            const float xm[8] = {xa.x,xa.y,xa.z,xa.w, xb.x,xb.y,xb.z,xb.w};
            #pragma unroll
            for (int i = 0; i < 8; ++i) {
                acc[i][0] += xm[i]*wv.x; acc[i][1] += xm[i]*wv.y;
                acc[i][2] += xm[i]*wv.z; acc[i][3] += xm[i]*wv.w;
            }
        }
        __syncthreads();
    }

    // write per-wave partial T3 tiles: buf[tk*2048 + m*32 + r]
    #pragma unroll
    for (int i = 0; i < 8; ++i) {
        float4 v = {acc[i][0], acc[i][1], acc[i][2], acc[i][3]};
        buf4[tk*512 + (tm*8 + i)*8 + tr] = v;
    }
    __syncthreads();

    // reduce over tk (8 floats = 2 f4 per thread), result at buf[0..2048)
    {
        float4 s0 = buf4[t*2], s1 = buf4[t*2 + 1];
        #pragma unroll
        for (int q = 1; q < 4; ++q) {
            float4 a = buf4[q*512 + t*2], c2 = buf4[q*512 + t*2 + 1];
            s0.x+=a.x; s0.y+=a.y; s0.z+=a.z; s0.w+=a.w;
            s1.x+=c2.x; s1.y+=c2.y; s1.z+=c2.z; s1.w+=c2.w;
        }
        __syncthreads();
        buf4[t*2] = s0; buf4[t*2 + 1] = s1;
        // reload N2 into buf[2048..4096)
        const float4* n24 = (const float4*)(ws + WS_N2);
        buf4[512 + t] = n24[t];
        buf4[768 + t] = n24[256 + t];   // covers 512 f4 with 2x256
    }
    __syncthreads();

    // phase 3: T5[r3,s2] = sum_m T3[m,r3]*N2[m,s2] -> buf[4096..5120)
    {
        const int r3  = t >> 3;
        const int s2b = (t & 7) * 4;
        float a0=0.f, a1=0.f, a2=0.f, a3=0.f;
        #pragma unroll 8
        for (int m = 0; m < 64; ++m) {
            float av = buf[m*32 + r3];
            const float* n = &buf[2048 + m*32 + s2b];
            a0 += av*n[0]; a1 += av*n[1]; a2 += av*n[2]; a3 += av*n[3];
        }
        float* d = &buf[4096 + r3*32 + s2b];
        d[0]=a0; d[1]=a1; d[2]=a2; d[3]=a3;
    }
    __syncthreads();

    // phase 4: z[ro] = sum_k T5[k]*core[k,ro]; 16 k-slices x 16 ro-pairs
    {
        const int ro2 = t & 15;
        const int kc  = t >> 4;
        const float2* core2 = (const float2*)core;
        float s0 = 0.f, s1 = 0.f;
        const int k0 = kc * 64;
        for (int k = k0; k < k0 + 64; ++k) {
            float tv = buf[4096 + k];
            float2 cv = core2[k*16 + ro2];
            s0 += tv*cv.x; s1 += tv*cv.y;
        }
        spart[kc*32 + ro2*2 + 0] = s0;
        spart[kc*32 + ro2*2 + 1] = s1;
    }
    __syncthreads();
    if (t < 32) {
        float s = 0.f;
        #pragma unroll
        for (int kc = 0; kc < 16; ++kc) s += spart[kc*32 + t];
        zout[b*32 + t] = s;
    }
}

// ---------------------------------------------------------------------------
// Kernel C: out[b,o] = sum_r z[b,r]*Wt[r,o] + bias[o]
// ---------------------------------------------------------------------------
__global__ __launch_bounds__(256) void out_kernel(
    const float* __restrict__ ws, const float* __restrict__ bias,
    float* __restrict__ out)
{
    __shared__ float sW[8192];   // Wt tile [32][256]
    __shared__ float sZt[2176];  // z tile transposed [32 ro][68]
    __shared__ float sB[256];
    const int t  = threadIdx.x;
    const int bt = blockIdx.x;
    const int ot = blockIdx.y;

    {
        const float4* wt4 = (const float4*)(ws + WS_WT);
        float4* d = (float4*)sW;
        #pragma unroll
        for (int i = 0; i < 8; ++i) {
            int idx = i*256 + t;
            int ro = idx >> 6, oc = idx & 63;
            d[idx] = wt4[ro*1024 + ot*64 + oc];
        }
    }
    {
        const float4* z4 = (const float4*)(ws + WS_Z) + bt*512;
        #pragma unroll
        for (int i = 0; i < 2; ++i) {
            int idx = i*256 + t;
            int bl = idx >> 3, r4 = idx & 7;
            float4 v = z4[idx];
            sZt[(r4*4 + 0)*68 + bl] = v.x;
            sZt[(r4*4 + 1)*68 + bl] = v.y;
            sZt[(r4*4 + 2)*68 + bl] = v.z;
            sZt[(r4*4 + 3)*68 + bl] = v.w;
        }
    }
    if (t < 64) {
        const float4* b4 = (const float4*)bias + ot*64;
        ((float4*)sB)[t] = b4[t];
    }
    __syncthreads();

    const int oc = t & 63;
    const int bg = t >> 6;
    const float4* sW4 = (const float4*)sW;
    const float4 bv = ((const float4*)sB)[oc];
    float4* out4 = (float4*)out;

    for (int bi = 0; bi < 16; bi += 4) {
        const int bl = bg*16 + bi;
        float4 a0 = bv, a1 = bv, a2 = bv, a3 = bv;
        #pragma unroll
        for (int ro = 0; ro < 32; ++ro) {
            float4 w = sW4[ro*64 + oc];
            float4 z = *(const float4*)&sZt[ro*68 + bl];
            a0.x += z.x*w.x; a0.y += z.x*w.y; a0.z += z.x*w.z; a0.w += z.x*w.w;
            a1.x += z.y*w.x; a1.y += z.y*w.y; a1.z += z.y*w.z; a1.w += z.y*w.w;
            a2.x += z.z*w.x; a2.y += z.z*w.y; a2.z += z.z*w.z; a2.w += z.z*w.w;
            a3.x += z.w*w.x; a3.y += z.w*w.y; a3.z += z.w*w.z; a3.w += z.w*w.w;
        }
        const size_t obase = (size_t)(bt*64 + bl) * 1024 + ot*64 + oc;
        out4[obase + 0*1024] = a0;
        out4[obase + 1*1024] = a1;
        out4[obase + 2*1024] = a2;
        out4[obase + 3*1024] = a3;
    }
}

extern "C" void kernel_launch(void* const* d_in, const int* in_sizes, int n_in,
                              void* d_out, int out_size, void* d_ws, size_t ws_size,
                              hipStream_t stream)
{
    const float* x    = (const float*)d_in[0];
    const float* f0   = (const float*)d_in[1];
    const float* f1   = (const float*)d_in[2];
    const float* f2   = (const float*)d_in[3];
    const float* f3   = (const float*)d_in[4];
    const float* f4   = (const float*)d_in[5];
    const float* core = (const float*)d_in[6];
    const float* g0   = (const float*)d_in[7];
    const float* g1   = (const float*)d_in[8];
    const float* g2   = (const float*)d_in[9];
    const float* bias = (const float*)d_in[10];
    float* ws  = (float*)d_ws;
    float* out = (float*)d_out;

    precompute_kernel<<<41, 256, 0, stream>>>(f0, f1, f2, f3, f4, g0, g1, g2, ws);
    main_kernel<<<1024, 256, 0, stream>>>(x, core, ws, ws + WS_Z);
    out_kernel<<<dim3(16, 16), 256, 0, stream>>>(ws, bias, out);
}